// Round 11
// baseline (2454.780 us; speedup 1.0000x reference)
//
#include <hip/hip_runtime.h>
#include <hip/hip_bf16.h>

#define HIDDEN   1024
#define XDIM     130
#define CONDDIM  44
#define INDIM    174      // XDIM + CONDDIM
#define NSTEP    16
#define BP       4096     // effective batch (64*64)
#define K0P      1088     // 1024 (h0) + 44 (y) + 20 pad  -> 34 K-tiles of 32 (even)
#define K1P      2048     // 1024 (h0') + 1024 (h1)       -> 64 K-tiles of 32 (even)
#define GN       4096     // 4*HIDDEN gate dim
#define LGN      256      // padded logits cols (130 -> 256)

typedef __bf16 bf16x8 __attribute__((ext_vector_type(8)));
typedef float  f32x4  __attribute__((ext_vector_type(4)));

// fused gate column order: n in [0,4096) -> q=(n>>4)&3 (gate), j=((n>>6)<<4)|(n&15)
__device__ __forceinline__ int fused_row(int n) {
  const int q = (n >> 4) & 3;
  const int j = ((n >> 6) << 4) | (n & 15);
  return q * HIDDEN + j;
}

// ---------------------------------------------------------------- helpers
__device__ __forceinline__ void g2lds16(const void* g, void* l) {
  __builtin_amdgcn_global_load_lds(
      (const __attribute__((address_space(1))) void*)g,
      (__attribute__((address_space(3))) void*)l, 16, 0, 0);
}

__device__ __forceinline__ float sigm(float x)  { return 1.f / (1.f + __expf(-x)); }
__device__ __forceinline__ float tanhfast(float x) { return 2.f / (1.f + __expf(-2.f * x)) - 1.f; }

// ---------------------------------------------------------------- 256^2 GEMM + LSTM cell, B-direct-to-regs
// gates(4096 x 4096) = A(4096 x K) @ W(4096 x K)^T, fused-gate column order.
// LDS-BW analysis (R10 post-mortem): with A AND B in LDS, wave re-reads put the
// LDS read pipe at ~93% of its 85 B/cyc ceiling -> MfmaUtil pinned at ~35%.
// Here B comes from a fragment-packed global buffer straight into VGPRs
// (coalesced lane*16B loads, L2-resident, double-buffered b0/b1 across K-tiles);
// LDS holds only A (4 x 16 KB buffers, 3-ahead prefetch via global_load_lds).
// Counted vmcnt(8) at K-tile bottom = {A(t+2):2, B(t+1):4, A(t+3):2} younger ops
// guarantee A(t+1) landed; never vmcnt(0) mid-loop.
// Bp layout: elem = (((nb*NT + t)*4 + wn)*4 + nf)*512 + lane*8 + e
//   -> value = Wfused[nb*256 + wn*64 + nf*16 + (lane&15)][t*32 + (lane>>4)*8 + e]
template<bool FB>
__global__ __launch_bounds__(512, 2)
void gemm256_cell_k(const __hip_bfloat16* __restrict__ A,
                    const __hip_bfloat16* __restrict__ Bp,   // fragment-packed weights
                    int K, int NT,                            // NT = K/32 (even, >= 4)
                    const float* __restrict__ bcomb,     // 4096, fused order
                    const float* __restrict__ W0T,       // 130 x 4096 fused order (FB only)
                    const int*   __restrict__ idx,       // per-row feedback index (FB only)
                    float* __restrict__ c,
                    __hip_bfloat16* __restrict__ h1dst, int ld1,
                    __hip_bfloat16* __restrict__ h2dst, int ld2)
{
  // 4 buffers x A[256][32] bf16 = 64 KB (A only)
  __shared__ __align__(16) __hip_bfloat16 lds[4 * 8192];

  const int tid  = threadIdx.x;
  const int w    = tid >> 6;        // wave 0..7
  const int lane = tid & 63;
  const int bid  = blockIdx.x;      // 256 blocks
  const int swz  = ((bid & 7) << 5) | (bid >> 3);   // XCD-chunked (256 % 8 == 0)
  const int m0   = (swz >> 4) * 256;
  const int nb   = swz & 15;        // n-block (256 cols)
  const int n0   = nb * 256;
  const int wm   = w >> 2;          // 0..1 : row half
  const int wn   = w & 3;           // 0..3 : col quarter
  const int fr   = lane & 15;
  // A-side swizzle (as R4): 16B k-slot XOR ((row>>1)&3); LDS linear, source pre-XORed
  const int kqs  = (((lane >> 4) ^ ((fr >> 1) & 3)) * 8);
  const int sr   = lane >> 2;       // staging row within 16-row issue
  const int sc   = (((lane & 3) ^ ((sr >> 1) & 3)) * 8);

  f32x4 acc[8][4] = {};

  // A staging: per wave 2 issues of 16 rows x 64 B
  #define STAGE_A(t, i)                                                             \
    g2lds16(A + (size_t)(m0 + w * 32 + (i) * 16 + sr) * K + ((t) * 32 + sc),        \
            (void*)(lds + ((t) & 3) * 8192 + w * 1024 + (i) * 512))

  // B fragments: coalesced global -> VGPR
  const __hip_bfloat16* BpBase =
      Bp + (((size_t)nb * NT * 4 + wn) << 11) + (size_t)lane * 8;
  #define LOAD_B(t, dst) do {                                                       \
    const __hip_bfloat16* p_ = BpBase + (size_t)(t) * 8192;                         \
    _Pragma("unroll") for (int nf_ = 0; nf_ < 4; ++nf_)                             \
      dst[nf_] = *reinterpret_cast<const bf16x8*>(p_ + nf_ * 512);                  \
  } while (0)

  // one K-tile: MFMA with bc_, prefetch B(t+1) into bn_, stage A(t+3)
  #define KTILE(t, bc_, bn_) do {                                                   \
    const __hip_bfloat16* As = lds + ((t) & 3) * 8192;                              \
    if ((t) + 1 < NT) LOAD_B((t) + 1, bn_);                                         \
    _Pragma("unroll") for (int half = 0; half < 2; ++half) {                        \
      if ((t) + 3 < NT) { if (half == 0) STAGE_A((t) + 3, 0);                       \
                          else           STAGE_A((t) + 3, 1); }                     \
      bf16x8 afr[4];                                                                \
      _Pragma("unroll") for (int q = 0; q < 4; ++q)                                 \
        afr[q] = *reinterpret_cast<const bf16x8*>(                                  \
            &As[(wm * 128 + (half * 4 + q) * 16 + fr) * 32 + kqs]);                 \
      __builtin_amdgcn_s_setprio(1);                                                \
      _Pragma("unroll") for (int q = 0; q < 4; ++q)                                 \
        _Pragma("unroll") for (int nf = 0; nf < 4; ++nf)                            \
          acc[half * 4 + q][nf] = __builtin_amdgcn_mfma_f32_16x16x32_bf16(          \
              afr[q], bc_[nf], acc[half * 4 + q][nf], 0, 0, 0);                     \
      __builtin_amdgcn_s_setprio(0);                                                \
    }                                                                               \
    if ((t) + 1 < NT) {                                                             \
      if ((t) + 3 < NT)      asm volatile("s_waitcnt vmcnt(8)" ::: "memory");       \
      else if ((t) + 2 < NT) asm volatile("s_waitcnt vmcnt(6)" ::: "memory");       \
      else                   asm volatile("s_waitcnt vmcnt(4)" ::: "memory");       \
      __builtin_amdgcn_s_barrier();                                                 \
    }                                                                               \
  } while (0)

  bf16x8 b0[4], b1[4];

  // prologue: A(0); B(0)->b0; A(1); A(2). A(0) landed when <=8 younger in flight.
  STAGE_A(0, 0); STAGE_A(0, 1);
  LOAD_B(0, b0);
  STAGE_A(1, 0); STAGE_A(1, 1);
  STAGE_A(2, 0); STAGE_A(2, 1);
  asm volatile("s_waitcnt vmcnt(8)" ::: "memory");
  __builtin_amdgcn_s_barrier();

  for (int t = 0; t < NT; t += 2) {   // NT even: static b0/b1 alternation
    KTILE(t,     b0, b1);
    KTILE(t + 1, b1, b0);
  }
  #undef KTILE
  #undef LOAD_B
  #undef STAGE_A

  // ---- fused LSTM cell epilogue ----
  const int fq = lane >> 4;
  const int cb = n0 + wn * 64;            // quadrant col base (multiple of 64)
  const int j  = ((cb >> 6) << 4) | fr;   // this lane's hidden index

  const float bs0 = bcomb[cb + fr];
  const float bs1 = bcomb[cb + 16 + fr];
  const float bs2 = bcomb[cb + 32 + fr];
  const float bs3 = bcomb[cb + 48 + fr];

  #pragma unroll
  for (int mf = 0; mf < 8; ++mf) {
    #pragma unroll
    for (int r = 0; r < 4; ++r) {
      const int b = m0 + wm * 128 + mf * 16 + fq * 4 + r;
      float gi = acc[mf][0][r] + bs0;
      float gf = acc[mf][1][r] + bs1;
      float gg = acc[mf][2][r] + bs2;
      float go = acc[mf][3][r] + bs3;
      if (FB) {
        const float* wr = W0T + (size_t)idx[b] * GN;
        gi += wr[cb + fr];
        gf += wr[cb + 16 + fr];
        gg += wr[cb + 32 + fr];
        go += wr[cb + 48 + fr];
      }
      const size_t ci = (size_t)b * HIDDEN + j;
      const float cn = sigm(gf) * c[ci] + sigm(gi) * tanhfast(gg);
      c[ci] = cn;
      const float hn = sigm(go) * tanhfast(cn);
      const __hip_bfloat16 hb = __float2bfloat16(hn);
      h1dst[(size_t)b * ld1 + j] = hb;
      if (h2dst) h2dst[(size_t)b * ld2 + j] = hb;
    }
  }
}

// ---------------------------------------------------------------- logits GEMM (64x128 tile, 128 blocks)
__global__ __launch_bounds__(256, 4)
void gemm_bt64_k(const __hip_bfloat16* __restrict__ A, int lda,
                 const __hip_bfloat16* __restrict__ W, int ldw,
                 float* __restrict__ C, int ldc, int K)
{
  __shared__ __align__(16) __hip_bfloat16 As[64 * 32];    // 4 KB
  __shared__ __align__(16) __hip_bfloat16 Bs[128 * 32];   // 8 KB

  const int tid  = threadIdx.x;
  const int w    = tid >> 6;        // wave 0..3
  const int lane = tid & 63;
  const int m0 = blockIdx.y * 64;
  const int n0 = blockIdx.x * 128;
  const int wm = w >> 1;            // 0..1 : 32-row half
  const int wn = w & 1;             // 0..1 : 64-col half
  const int fr = lane & 15;
  const int kqs = (((lane >> 4) ^ ((fr >> 1) & 3)) * 8);   // swizzled read slot
  const int sr  = lane >> 2;
  const int sc  = (((lane & 3) ^ ((sr >> 1) & 3)) * 8);    // pre-swizzled source

  f32x4 acc[2][4] = {};

  for (int k0 = 0; k0 < K; k0 += 32) {
    __syncthreads();
    g2lds16(A + (size_t)(m0 + w * 16 + sr) * lda + (k0 + sc), (void*)(As + (w * 16) * 32));
    g2lds16(W + (size_t)(n0 + w * 16 + sr) * ldw + (k0 + sc), (void*)(Bs + (w * 16) * 32));
    g2lds16(W + (size_t)(n0 + 64 + w * 16 + sr) * ldw + (k0 + sc), (void*)(Bs + (64 + w * 16) * 32));
    __syncthreads();

    bf16x8 af[2], bw[4];
    #pragma unroll
    for (int i = 0; i < 2; ++i)
      af[i] = *reinterpret_cast<const bf16x8*>(&As[(wm * 32 + i * 16 + fr) * 32 + kqs]);
    #pragma unroll
    for (int j = 0; j < 4; ++j)
      bw[j] = *reinterpret_cast<const bf16x8*>(&Bs[(wn * 64 + j * 16 + fr) * 32 + kqs]);
    #pragma unroll
    for (int i = 0; i < 2; ++i)
      #pragma unroll
      for (int j = 0; j < 4; ++j)
        acc[i][j] = __builtin_amdgcn_mfma_f32_16x16x32_bf16(af[i], bw[j], acc[i][j], 0, 0, 0);
  }

  const int fq = lane >> 4;
  #pragma unroll
  for (int i = 0; i < 2; ++i)
    #pragma unroll
    for (int j = 0; j < 4; ++j)
      #pragma unroll
      for (int r = 0; r < 4; ++r) {
        const int row = m0 + wm * 32 + i * 16 + fq * 4 + r;
        const int col = n0 + wn * 64 + j * 16 + fr;
        C[(size_t)row * ldc + col] = acc[i][j][r];
      }
}

// ---------------------------------------------------------------- log_softmax + argmax + y staging
__global__ void smax_k(const float* __restrict__ LG,   // 4096 x LGN logits (no bias yet)
                       const float* __restrict__ bfv,  // bf (130)
                       float* __restrict__ out, int t,
                       const float* __restrict__ x,
                       __hip_bfloat16* __restrict__ A0next,
                       int* __restrict__ idx)
{
  const int b    = blockIdx.x;
  const int lane = threadIdx.x;   // 64
  const float NINF = -__builtin_inff();
  const float* lg = LG + (size_t)b * LGN;

  const int c1 = lane + 64, c2 = lane + 128;
  float v0 = lg[lane] + bfv[lane];
  float v1 = lg[c1] + bfv[c1];
  float v2 = (c2 < XDIM) ? lg[c2] + bfv[c2] : NINF;

  float m = fmaxf(v0, fmaxf(v1, v2));
  #pragma unroll
  for (int o = 32; o > 0; o >>= 1) m = fmaxf(m, __shfl_xor(m, o, 64));

  int bi = 0x7fffffff;
  if (v0 == m) bi = lane;
  if (v1 == m) bi = min(bi, c1);
  if (v2 == m) bi = min(bi, c2);
  #pragma unroll
  for (int o = 32; o > 0; o >>= 1) bi = min(bi, __shfl_xor(bi, o, 64));

  float s = __expf(v0 - m) + __expf(v1 - m) + ((c2 < XDIM) ? __expf(v2 - m) : 0.f);
  #pragma unroll
  for (int o = 32; o > 0; o >>= 1) s += __shfl_xor(s, o, 64);
  const float lse = __logf(s);

  float* orow = out + ((size_t)b * NSTEP + t) * XDIM;
  orow[lane] = v0 - m - lse;
  orow[c1]   = v1 - m - lse;
  if (c2 < XDIM) orow[c2] = v2 - m - lse;
  if (lane == 0) idx[b] = bi;

  if (t + 1 < NSTEP) {   // stage next step's y (+ zero pad) into A0next cols 1024..1087
    const float yv = (lane < CONDDIM)
        ? x[((size_t)b * NSTEP + (t + 1)) * INDIM + XDIM + lane] : 0.f;
    A0next[(size_t)b * K0P + HIDDEN + lane] = __float2bfloat16(yv);
  }
}

// ---------------------------------------------------------------- init + weight packing
__global__ void init_k(const float* __restrict__ z, const float* __restrict__ x,
                       float* __restrict__ c0, float* __restrict__ c1,
                       __hip_bfloat16* __restrict__ A0, __hip_bfloat16* __restrict__ A1,
                       int* __restrict__ idx)
{
  const int t = blockIdx.x * blockDim.x + threadIdx.x;
  if (t >= BP * K1P) return;
  const int b = t >> 11;
  const int j = t & 2047;
  if (j >= HIDDEN)   // A1 second half: h1(-1) = z
    A1[(size_t)b * K1P + j] = __float2bfloat16(z[(size_t)b * HIDDEN + (j - HIDDEN)]);
  if (j < HIDDEN) {
    c0[(size_t)b * HIDDEN + j] = 0.f;
    c1[(size_t)b * HIDDEN + j] = 0.f;
    A0[(size_t)b * K0P + j] = __float2bfloat16(z[(size_t)b * HIDDEN + j]);  // h0(-1) = z
  } else if (j < HIDDEN + 64) {                     // y_0 + zero pad
    const int k = j - HIDDEN;
    const float yv = (k < CONDDIM) ? x[((size_t)b * NSTEP) * INDIM + XDIM + k] : 0.f;
    A0[(size_t)b * K0P + j] = __float2bfloat16(yv);
  }
  if (j == 0) idx[b] = 1;   // o0 one-hot at index 1
}

// fragment-packed weights, layer 0: cols = [Whh0 | Wih0_y | pad], K = K0P
__global__ void packB0_k(const float* __restrict__ Wih0, const float* __restrict__ Whh0,
                         __hip_bfloat16* __restrict__ Bp)
{
  const int NT = K0P / 32;
  const long long E = (long long)blockIdx.x * blockDim.x + threadIdx.x;
  if (E >= (long long)GN * K0P) return;
  const int e    = E & 7;
  const int lane = (E >> 3) & 63;
  const int nf   = (E >> 9) & 3;
  const int wn   = (E >> 11) & 3;
  const long long rem = E >> 13;
  const int t  = (int)(rem % NT);
  const int nb = (int)(rem / NT);
  const int n   = nb * 256 + wn * 64 + nf * 16 + (lane & 15);
  const int k   = t * 32 + (lane >> 4) * 8 + e;
  const int row = fused_row(n);
  float v = 0.f;
  if (k < HIDDEN)                v = Whh0[(size_t)row * HIDDEN + k];
  else if (k < HIDDEN + CONDDIM) v = Wih0[(size_t)row * INDIM + XDIM + (k - HIDDEN)];
  Bp[E] = __float2bfloat16(v);
}

// fragment-packed weights, layer 1: cols = [Wih1 | Whh1], K = K1P
__global__ void packB1_k(const float* __restrict__ Wih1, const float* __restrict__ Whh1,
                         __hip_bfloat16* __restrict__ Bp)
{
  const int NT = K1P / 32;
  const long long E = (long long)blockIdx.x * blockDim.x + threadIdx.x;
  if (E >= (long long)GN * K1P) return;
  const int e    = E & 7;
  const int lane = (E >> 3) & 63;
  const int nf   = (E >> 9) & 3;
  const int wn   = (E >> 11) & 3;
  const long long rem = E >> 13;
  const int t  = (int)(rem % NT);
  const int nb = (int)(rem / NT);
  const int n   = nb * 256 + wn * 64 + nf * 16 + (lane & 15);
  const int k   = t * 32 + (lane >> 4) * 8 + e;
  const int row = fused_row(n);
  const float v = (k < HIDDEN) ? Wih1[(size_t)row * HIDDEN + k]
                               : Whh1[(size_t)row * HIDDEN + (k - HIDDEN)];
  Bp[E] = __float2bfloat16(v);
}

__global__ void packbias_k(const float* __restrict__ bih, const float* __restrict__ bhh,
                           float* __restrict__ bc)
{
  const int n = blockIdx.x * blockDim.x + threadIdx.x;
  if (n >= GN) return;
  const int row = fused_row(n);
  bc[n] = bih[row] + bhh[row];
}

__global__ void packf_k(const float* __restrict__ Wf, __hip_bfloat16* __restrict__ Wfp)
{
  const int t = blockIdx.x * blockDim.x + threadIdx.x;
  if (t >= LGN * HIDDEN) return;
  const int r = t >> 10, k = t & 1023;
  const float v = (r < XDIM) ? Wf[(size_t)r * HIDDEN + k] : 0.f;
  Wfp[t] = __float2bfloat16(v);
}

__global__ void packt_k(const float* __restrict__ Wih0, float* __restrict__ W0T)
{
  const int t = blockIdx.x * blockDim.x + threadIdx.x;
  if (t >= XDIM * GN) return;
  const int e = t >> 12, n = t & 4095;      // W0T[e][n] = Wih0[fused_row(n)][e]
  W0T[t] = Wih0[(size_t)fused_row(n) * INDIM + e];
}

// ---------------------------------------------------------------- launch
extern "C" void kernel_launch(void* const* d_in, const int* in_sizes, int n_in,
                              void* d_out, int out_size, void* d_ws, size_t ws_size,
                              hipStream_t stream)
{
  const float* z    = (const float*)d_in[0];
  const float* x    = (const float*)d_in[1];
  const float* Wih0 = (const float*)d_in[2];
  const float* Whh0 = (const float*)d_in[3];
  const float* bih0 = (const float*)d_in[4];
  const float* bhh0 = (const float*)d_in[5];
  const float* Wih1 = (const float*)d_in[6];
  const float* Whh1 = (const float*)d_in[7];
  const float* bih1 = (const float*)d_in[8];
  const float* bhh1 = (const float*)d_in[9];
  const float* Wf   = (const float*)d_in[10];
  const float* bfv  = (const float*)d_in[11];
  float* out = (float*)d_out;

  char* ws = (char*)d_ws;
  size_t off = 0;
  auto alloc = [&](size_t bytes) { void* p = ws + off; off += (bytes + 255) & ~(size_t)255; return p; };

  float*          LG  = (float*)         alloc((size_t)BP * LGN * 4);      // logits
  __hip_bfloat16* A0a = (__hip_bfloat16*)alloc((size_t)BP * K0P * 2);
  __hip_bfloat16* A0b = (__hip_bfloat16*)alloc((size_t)BP * K0P * 2);
  __hip_bfloat16* A1a = (__hip_bfloat16*)alloc((size_t)BP * K1P * 2);
  __hip_bfloat16* A1b = (__hip_bfloat16*)alloc((size_t)BP * K1P * 2);
  __hip_bfloat16* Bp0 = (__hip_bfloat16*)alloc((size_t)GN * K0P * 2);
  __hip_bfloat16* Bp1 = (__hip_bfloat16*)alloc((size_t)GN * K1P * 2);
  __hip_bfloat16* Wfp = (__hip_bfloat16*)alloc((size_t)LGN * HIDDEN * 2);
  float*          W0T = (float*)         alloc((size_t)XDIM * GN * 4);
  float*          bc0 = (float*)         alloc((size_t)GN * 4);
  float*          bc1 = (float*)         alloc((size_t)GN * 4);
  float*          c0  = (float*)         alloc((size_t)BP * HIDDEN * 4);
  float*          c1  = (float*)         alloc((size_t)BP * HIDDEN * 4);
  int*            idx = (int*)           alloc((size_t)BP * 4);
  (void)ws_size; (void)in_sizes; (void)n_in; (void)out_size;

  packB0_k<<<(GN * K0P + 255) / 256, 256, 0, stream>>>(Wih0, Whh0, Bp0);
  packB1_k<<<(GN * K1P + 255) / 256, 256, 0, stream>>>(Wih1, Whh1, Bp1);
  packbias_k<<<(GN + 255) / 256, 256, 0, stream>>>(bih0, bhh0, bc0);
  packbias_k<<<(GN + 255) / 256, 256, 0, stream>>>(bih1, bhh1, bc1);
  packf_k<<<(LGN * HIDDEN + 255) / 256, 256, 0, stream>>>(Wf, Wfp);
  packt_k<<<(XDIM * GN + 255) / 256, 256, 0, stream>>>(Wih0, W0T);
  init_k<<<(BP * K1P + 255) / 256, 256, 0, stream>>>(z, x, c0, c1, A0a, A1a, idx);

  for (int t = 0; t < NSTEP; ++t) {
    __hip_bfloat16* A0c = (t & 1) ? A0b : A0a;
    __hip_bfloat16* A0n = (t & 1) ? A0a : A0b;
    __hip_bfloat16* A1c = (t & 1) ? A1b : A1a;
    __hip_bfloat16* A1n = (t & 1) ? A1a : A1b;

    // layer 0: gates = [h0|y] @ [Whh0|Wih0_y]^T, fused cell -> h0'
    gemm256_cell_k<true><<<256, 512, 0, stream>>>(
        A0c, Bp0, K0P, K0P / 32, bc0, W0T, idx, c0,
        A1c, K1P,        // h0' -> A1 (current) first half, read by GEMM1 this step
        A0n, K0P);       // h0' -> A0 (next step)
    // layer 1: gates = [h0'|h1] @ [Wih1|Whh1]^T, fused cell -> h1'
    gemm256_cell_k<false><<<256, 512, 0, stream>>>(
        A1c, Bp1, K1P, K1P / 32, bc1, nullptr, nullptr, c1,
        A1n + HIDDEN, K1P,   // h1' -> A1 (next) second half
        nullptr, 0);
    // logits = h1' @ Wf^T  (64x128 tile, 128 blocks)
    gemm_bt64_k<<<dim3(LGN / 128, BP / 64), dim3(256), 0, stream>>>(
        A1n + HIDDEN, K1P, Wfp, HIDDEN, LG, LGN, HIDDEN);
    smax_k<<<BP, 64, 0, stream>>>(LG, bfv, out, t, x, A0n, idx);
  }
}

// Round 12
// 1841.949 us; speedup vs baseline: 1.3327x; 1.3327x over previous
//
#include <hip/hip_runtime.h>
#include <hip/hip_bf16.h>

#define HIDDEN   1024
#define XDIM     130
#define CONDDIM  44
#define INDIM    174      // XDIM + CONDDIM
#define NSTEP    16
#define BP       4096     // effective batch (64*64)
#define K0P      1088     // 1024 (h0) + 44 (y) + 20 pad ; bf16: 34 tiles of 32, i8: 17 tiles of 64
#define K1P      2048     // 1024 (h0') + 1024 (h1)
#define GN       4096     // 4*HIDDEN gate dim
#define LGN      256      // padded logits cols (130 -> 256)

typedef __bf16 bf16x8 __attribute__((ext_vector_type(8)));
typedef float  f32x4  __attribute__((ext_vector_type(4)));
typedef int    i32x4  __attribute__((ext_vector_type(4)));

// fused gate column order: n in [0,4096) -> q=(n>>4)&3 (gate), j=((n>>6)<<4)|(n&15)
__device__ __forceinline__ int fused_row(int n) {
  const int q = (n >> 4) & 3;
  const int j = ((n >> 6) << 4) | (n & 15);
  return q * HIDDEN + j;
}

__device__ __forceinline__ void g2lds16(const void* g, void* l) {
  __builtin_amdgcn_global_load_lds(
      (const __attribute__((address_space(1))) void*)g,
      (__attribute__((address_space(3))) void*)l, 16, 0, 0);
}

__device__ __forceinline__ float sigm(float x)  { return 1.f / (1.f + __expf(-x)); }
__device__ __forceinline__ float tanhfast(float x) { return 2.f / (1.f + __expf(-2.f * x)) - 1.f; }

__device__ __forceinline__ signed char q127(float v) {
  int q = __float2int_rn(v * 127.f);
  q = q > 127 ? 127 : (q < -127 ? -127 : q);
  return (signed char)q;
}

// ================================================================ bf16 gate GEMM + cell (t=0 only; R4-proven)
// Epilogue emits int8 h (scale 127) and/or bf16 h.
template<bool FB>
__global__ __launch_bounds__(512, 2)
void gemm_bf_cell_k(const __hip_bfloat16* __restrict__ A,
                    const __hip_bfloat16* __restrict__ W, int K,
                    const float* __restrict__ bcomb,
                    const float* __restrict__ W0T,
                    const int*   __restrict__ idx,
                    float* __restrict__ c,
                    signed char* __restrict__ d1, int ld1,     // int8 h dest (or null)
                    signed char* __restrict__ d2, int ld2,     // int8 h dest (or null)
                    __hip_bfloat16* __restrict__ dbf, int ldbf) // bf16 h dest (or null)
{
  __shared__ __align__(16) __hip_bfloat16 lds[4 * 16384];   // 128 KB

  const int tid  = threadIdx.x;
  const int w    = tid >> 6;
  const int lane = tid & 63;
  const int bid  = blockIdx.x;
  const int swz  = ((bid & 7) << 5) | (bid >> 3);
  const int m0   = (swz >> 4) * 256;
  const int n0   = (swz & 15) * 256;
  const int wm   = w >> 2;
  const int wn   = w & 3;
  const int fr   = lane & 15;
  const int kqs  = (((lane >> 4) ^ ((fr >> 1) & 3)) * 8);
  const int sr   = lane >> 2;
  const int sc   = (((lane & 3) ^ ((sr >> 1) & 3)) * 8);
  const int NT   = K >> 5;

  f32x4 acc[8][4] = {};

  #define STAGE_A(t, d, i)                                                          \
    g2lds16(A + (size_t)(m0 + w * 32 + (i) * 16 + sr) * K + ((t) * 32 + sc),        \
            (void*)(lds + (d) * 16384 + w * 1024 + (i) * 512))
  #define STAGE_B(t, d, i)                                                          \
    g2lds16(W + (size_t)(n0 + w * 32 + (i) * 16 + sr) * K + ((t) * 32 + sc),        \
            (void*)(lds + (d) * 16384 + 8192 + w * 1024 + (i) * 512))

  const int npro = (NT < 3) ? NT : 3;
  for (int t = 0; t < npro; ++t) {
    STAGE_A(t, t, 0); STAGE_B(t, t, 0);
    STAGE_A(t, t, 1); STAGE_B(t, t, 1);
  }
  if (NT >= 3)      asm volatile("s_waitcnt vmcnt(8)" ::: "memory");
  else if (NT == 2) asm volatile("s_waitcnt vmcnt(4)" ::: "memory");
  else              asm volatile("s_waitcnt vmcnt(0)" ::: "memory");
  __builtin_amdgcn_s_barrier();

  for (int t = 0; t < NT; ++t) {
    const int d  = t & 3;
    const __hip_bfloat16* As = lds + d * 16384;
    const __hip_bfloat16* Bs = As + 8192;
    const int tp = t + 3;
    const int dp = tp & 3;
    const bool pf = tp < NT;

    bf16x8 bfr[4];
    #pragma unroll
    for (int nf = 0; nf < 4; ++nf)
      bfr[nf] = *reinterpret_cast<const bf16x8*>(&Bs[(wn * 64 + nf * 16 + fr) * 32 + kqs]);

    #pragma unroll
    for (int half = 0; half < 2; ++half) {
      if (pf) {
        if (half == 0) { STAGE_A(tp, dp, 0); STAGE_A(tp, dp, 1); }
        else           { STAGE_B(tp, dp, 0); STAGE_B(tp, dp, 1); }
      }
      bf16x8 afr[4];
      #pragma unroll
      for (int q = 0; q < 4; ++q)
        afr[q] = *reinterpret_cast<const bf16x8*>(&As[(wm * 128 + (half * 4 + q) * 16 + fr) * 32 + kqs]);
      __builtin_amdgcn_s_setprio(1);
      #pragma unroll
      for (int q = 0; q < 4; ++q)
        #pragma unroll
        for (int nf = 0; nf < 4; ++nf)
          acc[half * 4 + q][nf] =
              __builtin_amdgcn_mfma_f32_16x16x32_bf16(afr[q], bfr[nf], acc[half * 4 + q][nf], 0, 0, 0);
      __builtin_amdgcn_s_setprio(0);
    }

    if (t + 3 < NT)      asm volatile("s_waitcnt vmcnt(8)" ::: "memory");
    else if (t + 2 < NT) asm volatile("s_waitcnt vmcnt(4)" ::: "memory");
    else if (t + 1 < NT) asm volatile("s_waitcnt vmcnt(0)" ::: "memory");
    if (t + 1 < NT) __builtin_amdgcn_s_barrier();
  }
  #undef STAGE_A
  #undef STAGE_B

  const int fq = lane >> 4;
  const int cb = n0 + wn * 64;
  const int j  = ((cb >> 6) << 4) | fr;

  const float bs0 = bcomb[cb + fr];
  const float bs1 = bcomb[cb + 16 + fr];
  const float bs2 = bcomb[cb + 32 + fr];
  const float bs3 = bcomb[cb + 48 + fr];

  #pragma unroll
  for (int mf = 0; mf < 8; ++mf) {
    #pragma unroll
    for (int r = 0; r < 4; ++r) {
      const int b = m0 + wm * 128 + mf * 16 + fq * 4 + r;
      float gi = acc[mf][0][r] + bs0;
      float gf = acc[mf][1][r] + bs1;
      float gg = acc[mf][2][r] + bs2;
      float go = acc[mf][3][r] + bs3;
      if (FB) {
        const float* wr = W0T + (size_t)idx[b] * GN;
        gi += wr[cb + fr];
        gf += wr[cb + 16 + fr];
        gg += wr[cb + 32 + fr];
        go += wr[cb + 48 + fr];
      }
      const size_t ci = (size_t)b * HIDDEN + j;
      const float cn = sigm(gf) * c[ci] + sigm(gi) * tanhfast(gg);
      c[ci] = cn;
      const float hn = sigm(go) * tanhfast(cn);
      const signed char hq = q127(hn);
      if (d1)  d1[(size_t)b * ld1 + j] = hq;
      if (d2)  d2[(size_t)b * ld2 + j] = hq;
      if (dbf) dbf[(size_t)b * ldbf + j] = __float2bfloat16(hn);
    }
  }
}

// ================================================================ int8 gate GEMM + cell (t>=1)
// Byte-identical geometry to the bf16 kernel (64B LDS rows, same swizzle/staging),
// but each K-tile covers K=64 via mfma_i32_16x16x64_i8: MFMA count, LDS traffic,
// staging bytes and barrier count per FLOP all halve.
// A: int8 = round(h*127) (h in [-1,1]); y cols store y/4 (x4 folded into W).
// W: int8 per-row scale Rmax/127; epilogue: gate = acc * Rmax/127^2 + bias.
template<bool FB>
__global__ __launch_bounds__(512, 2)
void gemm_i8_cell_k(const signed char* __restrict__ A,
                    const signed char* __restrict__ W, int K,   // K in bytes/elems
                    const float* __restrict__ bcomb,
                    const float* __restrict__ SC,        // 4096: Rmax/127^2, fused order
                    const float* __restrict__ W0T,
                    const int*   __restrict__ idx,
                    float* __restrict__ c,
                    signed char* __restrict__ d1, int ld1,
                    signed char* __restrict__ d2, int ld2,
                    __hip_bfloat16* __restrict__ dbf, int ldbf)
{
  __shared__ __align__(16) signed char lds[4 * 32768];   // 4 buf x (A 16KB + B 16KB)

  const int tid  = threadIdx.x;
  const int w    = tid >> 6;
  const int lane = tid & 63;
  const int bid  = blockIdx.x;
  const int swz  = ((bid & 7) << 5) | (bid >> 3);
  const int m0   = (swz >> 4) * 256;
  const int n0   = (swz & 15) * 256;
  const int wm   = w >> 2;
  const int wn   = w & 3;
  const int fr   = lane & 15;
  const int kqs  = (((lane >> 4) ^ ((fr >> 1) & 3)) * 16);   // byte offsets (same banks as bf16 ver)
  const int sr   = lane >> 2;
  const int sc   = (((lane & 3) ^ ((sr >> 1) & 3)) * 16);
  const int NT   = K >> 6;          // K-tiles of 64 int8 elems (64 B rows)

  i32x4 acc[8][4] = {};

  #define STAGE_A(t, d, i)                                                          \
    g2lds16(A + (size_t)(m0 + w * 32 + (i) * 16 + sr) * K + ((t) * 64 + sc),        \
            (void*)(lds + (d) * 32768 + (w * 32 + (i) * 16) * 64))
  #define STAGE_B(t, d, i)                                                          \
    g2lds16(W + (size_t)(n0 + w * 32 + (i) * 16 + sr) * K + ((t) * 64 + sc),        \
            (void*)(lds + (d) * 32768 + 16384 + (w * 32 + (i) * 16) * 64))

  const int npro = (NT < 3) ? NT : 3;
  for (int t = 0; t < npro; ++t) {
    STAGE_A(t, t, 0); STAGE_B(t, t, 0);
    STAGE_A(t, t, 1); STAGE_B(t, t, 1);
  }
  if (NT >= 3)      asm volatile("s_waitcnt vmcnt(8)" ::: "memory");
  else if (NT == 2) asm volatile("s_waitcnt vmcnt(4)" ::: "memory");
  else              asm volatile("s_waitcnt vmcnt(0)" ::: "memory");
  __builtin_amdgcn_s_barrier();

  for (int t = 0; t < NT; ++t) {
    const int d  = t & 3;
    const signed char* As = lds + d * 32768;
    const signed char* Bs = As + 16384;
    const int tp = t + 3;
    const int dp = tp & 3;
    const bool pf = tp < NT;

    i32x4 bfr[4];
    #pragma unroll
    for (int nf = 0; nf < 4; ++nf)
      bfr[nf] = *reinterpret_cast<const i32x4*>(&Bs[(wn * 64 + nf * 16 + fr) * 64 + kqs]);

    #pragma unroll
    for (int half = 0; half < 2; ++half) {
      if (pf) {
        if (half == 0) { STAGE_A(tp, dp, 0); STAGE_A(tp, dp, 1); }
        else           { STAGE_B(tp, dp, 0); STAGE_B(tp, dp, 1); }
      }
      i32x4 afr[4];
      #pragma unroll
      for (int q = 0; q < 4; ++q)
        afr[q] = *reinterpret_cast<const i32x4*>(&As[(wm * 128 + (half * 4 + q) * 16 + fr) * 64 + kqs]);
      __builtin_amdgcn_s_setprio(1);
      #pragma unroll
      for (int q = 0; q < 4; ++q)
        #pragma unroll
        for (int nf = 0; nf < 4; ++nf)
          acc[half * 4 + q][nf] =
              __builtin_amdgcn_mfma_i32_16x16x64_i8(afr[q], bfr[nf], acc[half * 4 + q][nf], 0, 0, 0);
      __builtin_amdgcn_s_setprio(0);
    }

    if (t + 3 < NT)      asm volatile("s_waitcnt vmcnt(8)" ::: "memory");
    else if (t + 2 < NT) asm volatile("s_waitcnt vmcnt(4)" ::: "memory");
    else if (t + 1 < NT) asm volatile("s_waitcnt vmcnt(0)" ::: "memory");
    if (t + 1 < NT) __builtin_amdgcn_s_barrier();
  }
  #undef STAGE_A
  #undef STAGE_B

  const int fq = lane >> 4;
  const int cb = n0 + wn * 64;
  const int j  = ((cb >> 6) << 4) | fr;

  const float bs0 = bcomb[cb + fr],      sc0 = SC[cb + fr];
  const float bs1 = bcomb[cb + 16 + fr], sc1 = SC[cb + 16 + fr];
  const float bs2 = bcomb[cb + 32 + fr], sc2 = SC[cb + 32 + fr];
  const float bs3 = bcomb[cb + 48 + fr], sc3 = SC[cb + 48 + fr];

  #pragma unroll
  for (int mf = 0; mf < 8; ++mf) {
    #pragma unroll
    for (int r = 0; r < 4; ++r) {
      const int b = m0 + wm * 128 + mf * 16 + fq * 4 + r;
      float gi = (float)acc[mf][0][r] * sc0 + bs0;
      float gf = (float)acc[mf][1][r] * sc1 + bs1;
      float gg = (float)acc[mf][2][r] * sc2 + bs2;
      float go = (float)acc[mf][3][r] * sc3 + bs3;
      if (FB) {
        const float* wr = W0T + (size_t)idx[b] * GN;
        gi += wr[cb + fr];
        gf += wr[cb + 16 + fr];
        gg += wr[cb + 32 + fr];
        go += wr[cb + 48 + fr];
      }
      const size_t ci = (size_t)b * HIDDEN + j;
      const float cn = sigm(gf) * c[ci] + sigm(gi) * tanhfast(gg);
      c[ci] = cn;
      const float hn = sigm(go) * tanhfast(cn);
      const signed char hq = q127(hn);
      if (d1)  d1[(size_t)b * ld1 + j] = hq;
      if (d2)  d2[(size_t)b * ld2 + j] = hq;
      if (dbf) dbf[(size_t)b * ldbf + j] = __float2bfloat16(hn);
    }
  }
}

// ---------------------------------------------------------------- logits GEMM (64x128 tile, 128 blocks)
__global__ __launch_bounds__(256, 4)
void gemm_bt64_k(const __hip_bfloat16* __restrict__ A, int lda,
                 const __hip_bfloat16* __restrict__ W, int ldw,
                 float* __restrict__ C, int ldc, int K)
{
  __shared__ __align__(16) __hip_bfloat16 As[64 * 32];
  __shared__ __align__(16) __hip_bfloat16 Bs[128 * 32];

  const int tid  = threadIdx.x;
  const int w    = tid >> 6;
  const int lane = tid & 63;
  const int m0 = blockIdx.y * 64;
  const int n0 = blockIdx.x * 128;
  const int wm = w >> 1;
  const int wn = w & 1;
  const int fr = lane & 15;
  const int kqs = (((lane >> 4) ^ ((fr >> 1) & 3)) * 8);
  const int sr  = lane >> 2;
  const int sc  = (((lane & 3) ^ ((sr >> 1) & 3)) * 8);

  f32x4 acc[2][4] = {};

  for (int k0 = 0; k0 < K; k0 += 32) {
    __syncthreads();
    g2lds16(A + (size_t)(m0 + w * 16 + sr) * lda + (k0 + sc), (void*)(As + (w * 16) * 32));
    g2lds16(W + (size_t)(n0 + w * 16 + sr) * ldw + (k0 + sc), (void*)(Bs + (w * 16) * 32));
    g2lds16(W + (size_t)(n0 + 64 + w * 16 + sr) * ldw + (k0 + sc), (void*)(Bs + (64 + w * 16) * 32));
    __syncthreads();

    bf16x8 af[2], bw[4];
    #pragma unroll
    for (int i = 0; i < 2; ++i)
      af[i] = *reinterpret_cast<const bf16x8*>(&As[(wm * 32 + i * 16 + fr) * 32 + kqs]);
    #pragma unroll
    for (int j = 0; j < 4; ++j)
      bw[j] = *reinterpret_cast<const bf16x8*>(&Bs[(wn * 64 + j * 16 + fr) * 32 + kqs]);
    #pragma unroll
    for (int i = 0; i < 2; ++i)
      #pragma unroll
      for (int j = 0; j < 4; ++j)
        acc[i][j] = __builtin_amdgcn_mfma_f32_16x16x32_bf16(af[i], bw[j], acc[i][j], 0, 0, 0);
  }

  const int fq = lane >> 4;
  #pragma unroll
  for (int i = 0; i < 2; ++i)
    #pragma unroll
    for (int j = 0; j < 4; ++j)
      #pragma unroll
      for (int r = 0; r < 4; ++r) {
        const int row = m0 + wm * 32 + i * 16 + fq * 4 + r;
        const int col = n0 + wn * 64 + j * 16 + fr;
        C[(size_t)row * ldc + col] = acc[i][j][r];
      }
}

// ---------------------------------------------------------------- log_softmax + argmax + y staging (int8)
__global__ void smax_k(const float* __restrict__ LG,
                       const float* __restrict__ bfv,
                       float* __restrict__ out, int t,
                       const float* __restrict__ x,
                       signed char* __restrict__ A0next,   // int8, y cols store y/4 * 127
                       int* __restrict__ idx)
{
  const int b    = blockIdx.x;
  const int lane = threadIdx.x;   // 64
  const float NINF = -__builtin_inff();
  const float* lg = LG + (size_t)b * LGN;

  const int c1 = lane + 64, c2 = lane + 128;
  float v0 = lg[lane] + bfv[lane];
  float v1 = lg[c1] + bfv[c1];
  float v2 = (c2 < XDIM) ? lg[c2] + bfv[c2] : NINF;

  float m = fmaxf(v0, fmaxf(v1, v2));
  #pragma unroll
  for (int o = 32; o > 0; o >>= 1) m = fmaxf(m, __shfl_xor(m, o, 64));

  int bi = 0x7fffffff;
  if (v0 == m) bi = lane;
  if (v1 == m) bi = min(bi, c1);
  if (v2 == m) bi = min(bi, c2);
  #pragma unroll
  for (int o = 32; o > 0; o >>= 1) bi = min(bi, __shfl_xor(bi, o, 64));

  float s = __expf(v0 - m) + __expf(v1 - m) + ((c2 < XDIM) ? __expf(v2 - m) : 0.f);
  #pragma unroll
  for (int o = 32; o > 0; o >>= 1) s += __shfl_xor(s, o, 64);
  const float lse = __logf(s);

  float* orow = out + ((size_t)b * NSTEP + t) * XDIM;
  orow[lane] = v0 - m - lse;
  orow[c1]   = v1 - m - lse;
  if (c2 < XDIM) orow[c2] = v2 - m - lse;
  if (lane == 0) idx[b] = bi;

  if (t + 1 < NSTEP) {
    const float yv = (lane < CONDDIM)
        ? x[((size_t)b * NSTEP + (t + 1)) * INDIM + XDIM + lane] : 0.f;
    A0next[(size_t)b * K0P + HIDDEN + lane] = q127(yv * 0.25f);
  }
}

// ---------------------------------------------------------------- init + weight packing
__global__ void init_k(const float* __restrict__ z, const float* __restrict__ x,
                       float* __restrict__ c0, float* __restrict__ c1,
                       __hip_bfloat16* __restrict__ A0bf, __hip_bfloat16* __restrict__ A1bf,
                       int* __restrict__ idx)
{
  const int t = blockIdx.x * blockDim.x + threadIdx.x;
  if (t >= BP * K1P) return;
  const int b = t >> 11;
  const int j = t & 2047;
  if (j >= HIDDEN)
    A1bf[(size_t)b * K1P + j] = __float2bfloat16(z[(size_t)b * HIDDEN + (j - HIDDEN)]);
  if (j < HIDDEN) {
    c0[(size_t)b * HIDDEN + j] = 0.f;
    c1[(size_t)b * HIDDEN + j] = 0.f;
    A0bf[(size_t)b * K0P + j] = __float2bfloat16(z[(size_t)b * HIDDEN + j]);
  } else if (j < HIDDEN + 64) {
    const int k = j - HIDDEN;
    const float yv = (k < CONDDIM) ? x[((size_t)b * NSTEP) * INDIM + XDIM + k] : 0.f;
    A0bf[(size_t)b * K0P + j] = __float2bfloat16(yv);
  }
  if (j == 0) idx[b] = 1;
}

__global__ void pack0_k(const float* __restrict__ Wih0, const float* __restrict__ Whh0,
                        const float* __restrict__ bih0, const float* __restrict__ bhh0,
                        __hip_bfloat16* __restrict__ Wc0, float* __restrict__ bc0)
{
  const int t = blockIdx.x * blockDim.x + threadIdx.x;
  if (t >= GN * K0P) return;
  const int n = t / K0P, k = t % K0P;
  const int row = fused_row(n);
  float v = 0.f;
  if (k < HIDDEN)                v = Whh0[(size_t)row * HIDDEN + k];
  else if (k < HIDDEN + CONDDIM) v = Wih0[(size_t)row * INDIM + XDIM + (k - HIDDEN)];
  Wc0[t] = __float2bfloat16(v);
  if (k == 0) bc0[n] = bih0[row] + bhh0[row];
}

__global__ void pack1_k(const float* __restrict__ Wih1, const float* __restrict__ Whh1,
                        const float* __restrict__ bih1, const float* __restrict__ bhh1,
                        __hip_bfloat16* __restrict__ Wc1, float* __restrict__ bc1)
{
  const int t = blockIdx.x * blockDim.x + threadIdx.x;
  if (t >= GN * K1P) return;
  const int n = t >> 11, k = t & 2047;
  const int row = fused_row(n);
  const float v = (k < HIDDEN) ? Wih1[(size_t)row * HIDDEN + k]
                               : Whh1[(size_t)row * HIDDEN + (k - HIDDEN)];
  Wc1[t] = __float2bfloat16(v);
  if (k == 0) bc1[n] = bih1[row] + bhh1[row];
}

// per-fused-row max of |W'| (layer0: y cols x4-folded); SC = Rmax/127^2
__global__ void rowmax0_k(const float* __restrict__ Wih0, const float* __restrict__ Whh0,
                          float* __restrict__ RM, float* __restrict__ SC)
{
  const int n = blockIdx.x, lane = threadIdx.x;
  const int row = fused_row(n);
  float m = 1e-20f;
  for (int k = lane; k < HIDDEN; k += 64)  m = fmaxf(m, fabsf(Whh0[(size_t)row * HIDDEN + k]));
  for (int k = lane; k < CONDDIM; k += 64) m = fmaxf(m, 4.f * fabsf(Wih0[(size_t)row * INDIM + XDIM + k]));
  #pragma unroll
  for (int o = 32; o > 0; o >>= 1) m = fmaxf(m, __shfl_xor(m, o, 64));
  if (lane == 0) { RM[n] = m; SC[n] = m / 16129.f; }
}

__global__ void rowmax1_k(const float* __restrict__ Wih1, const float* __restrict__ Whh1,
                          float* __restrict__ RM, float* __restrict__ SC)
{
  const int n = blockIdx.x, lane = threadIdx.x;
  const int row = fused_row(n);
  float m = 1e-20f;
  for (int k = lane; k < HIDDEN; k += 64) {
    m = fmaxf(m, fabsf(Wih1[(size_t)row * HIDDEN + k]));
    m = fmaxf(m, fabsf(Whh1[(size_t)row * HIDDEN + k]));
  }
  #pragma unroll
  for (int o = 32; o > 0; o >>= 1) m = fmaxf(m, __shfl_xor(m, o, 64));
  if (lane == 0) { RM[n] = m; SC[n] = m / 16129.f; }
}

__global__ void packi0_k(const float* __restrict__ Wih0, const float* __restrict__ Whh0,
                         const float* __restrict__ RM, signed char* __restrict__ Bp)
{
  const int t = blockIdx.x * blockDim.x + threadIdx.x;
  if (t >= GN * K0P) return;
  const int n = t / K0P, k = t % K0P;
  const int row = fused_row(n);
  float v = 0.f;
  if (k < HIDDEN)                v = Whh0[(size_t)row * HIDDEN + k];
  else if (k < HIDDEN + CONDDIM) v = 4.f * Wih0[(size_t)row * INDIM + XDIM + (k - HIDDEN)];
  int q = __float2int_rn(v * (127.f / RM[n]));
  q = q > 127 ? 127 : (q < -127 ? -127 : q);
  Bp[t] = (signed char)q;
}

__global__ void packi1_k(const float* __restrict__ Wih1, const float* __restrict__ Whh1,
                         const float* __restrict__ RM, signed char* __restrict__ Bp)
{
  const int t = blockIdx.x * blockDim.x + threadIdx.x;
  if (t >= GN * K1P) return;
  const int n = t >> 11, k = t & 2047;
  const int row = fused_row(n);
  const float v = (k < HIDDEN) ? Wih1[(size_t)row * HIDDEN + k]
                               : Whh1[(size_t)row * HIDDEN + (k - HIDDEN)];
  int q = __float2int_rn(v * (127.f / RM[n]));
  q = q > 127 ? 127 : (q < -127 ? -127 : q);
  Bp[t] = (signed char)q;
}

__global__ void packf_k(const float* __restrict__ Wf, __hip_bfloat16* __restrict__ Wfp)
{
  const int t = blockIdx.x * blockDim.x + threadIdx.x;
  if (t >= LGN * HIDDEN) return;
  const int r = t >> 10, k = t & 1023;
  const float v = (r < XDIM) ? Wf[(size_t)r * HIDDEN + k] : 0.f;
  Wfp[t] = __float2bfloat16(v);
}

__global__ void packt_k(const float* __restrict__ Wih0, float* __restrict__ W0T)
{
  const int t = blockIdx.x * blockDim.x + threadIdx.x;
  if (t >= XDIM * GN) return;
  const int e = t >> 12, n = t & 4095;
  W0T[t] = Wih0[(size_t)fused_row(n) * INDIM + e];
}

// ---------------------------------------------------------------- launch
extern "C" void kernel_launch(void* const* d_in, const int* in_sizes, int n_in,
                              void* d_out, int out_size, void* d_ws, size_t ws_size,
                              hipStream_t stream)
{
  const float* z    = (const float*)d_in[0];
  const float* x    = (const float*)d_in[1];
  const float* Wih0 = (const float*)d_in[2];
  const float* Whh0 = (const float*)d_in[3];
  const float* bih0 = (const float*)d_in[4];
  const float* bhh0 = (const float*)d_in[5];
  const float* Wih1 = (const float*)d_in[6];
  const float* Whh1 = (const float*)d_in[7];
  const float* bih1 = (const float*)d_in[8];
  const float* bhh1 = (const float*)d_in[9];
  const float* Wf   = (const float*)d_in[10];
  const float* bfv  = (const float*)d_in[11];
  float* out = (float*)d_out;

  char* ws = (char*)d_ws;
  size_t off = 0;
  auto alloc = [&](size_t bytes) { void* p = ws + off; off += (bytes + 255) & ~(size_t)255; return p; };

  float*          LG   = (float*)         alloc((size_t)BP * LGN * 4);
  __hip_bfloat16* A0bf = (__hip_bfloat16*)alloc((size_t)BP * K0P * 2);   // t=0 only
  __hip_bfloat16* A1bf = (__hip_bfloat16*)alloc((size_t)BP * K1P * 2);   // t=0 only
  signed char*    A0i8a= (signed char*)   alloc((size_t)BP * K0P);
  signed char*    A0i8b= (signed char*)   alloc((size_t)BP * K0P);
  signed char*    A1i8a= (signed char*)   alloc((size_t)BP * K1P);
  signed char*    A1i8b= (signed char*)   alloc((size_t)BP * K1P);
  __hip_bfloat16* HL   = (__hip_bfloat16*)alloc((size_t)BP * HIDDEN * 2); // h1' bf16 for logits
  __hip_bfloat16* Wc0  = (__hip_bfloat16*)alloc((size_t)GN * K0P * 2);    // bf16 (t=0)
  __hip_bfloat16* Wc1  = (__hip_bfloat16*)alloc((size_t)GN * K1P * 2);
  signed char*    Bpi0 = (signed char*)   alloc((size_t)GN * K0P);
  signed char*    Bpi1 = (signed char*)   alloc((size_t)GN * K1P);
  __hip_bfloat16* Wfp  = (__hip_bfloat16*)alloc((size_t)LGN * HIDDEN * 2);
  float*          W0T  = (float*)         alloc((size_t)XDIM * GN * 4);
  float*          bc0  = (float*)         alloc((size_t)GN * 4);
  float*          bc1  = (float*)         alloc((size_t)GN * 4);
  float*          RM0  = (float*)         alloc((size_t)GN * 4);
  float*          SC0  = (float*)         alloc((size_t)GN * 4);
  float*          RM1  = (float*)         alloc((size_t)GN * 4);
  float*          SC1  = (float*)         alloc((size_t)GN * 4);
  float*          c0   = (float*)         alloc((size_t)BP * HIDDEN * 4);
  float*          c1   = (float*)         alloc((size_t)BP * HIDDEN * 4);
  int*            idx  = (int*)           alloc((size_t)BP * 4);
  (void)ws_size; (void)in_sizes; (void)n_in; (void)out_size;

  pack0_k<<<(GN * K0P + 255) / 256, 256, 0, stream>>>(Wih0, Whh0, bih0, bhh0, Wc0, bc0);
  pack1_k<<<(GN * K1P + 255) / 256, 256, 0, stream>>>(Wih1, Whh1, bih1, bhh1, Wc1, bc1);
  rowmax0_k<<<GN, 64, 0, stream>>>(Wih0, Whh0, RM0, SC0);
  rowmax1_k<<<GN, 64, 0, stream>>>(Wih1, Whh1, RM1, SC1);
  packi0_k<<<(GN * K0P + 255) / 256, 256, 0, stream>>>(Wih0, Whh0, RM0, Bpi0);
  packi1_k<<<(GN * K1P + 255) / 256, 256, 0, stream>>>(Wih1, Whh1, RM1, Bpi1);
  packf_k<<<(LGN * HIDDEN + 255) / 256, 256, 0, stream>>>(Wf, Wfp);
  packt_k<<<(XDIM * GN + 255) / 256, 256, 0, stream>>>(Wih0, W0T);
  init_k<<<(BP * K1P + 255) / 256, 256, 0, stream>>>(z, x, c0, c1, A0bf, A1bf, idx);

  for (int t = 0; t < NSTEP; ++t) {
    signed char* A0c = (t & 1) ? A0i8b : A0i8a;
    signed char* A0n = (t & 1) ? A0i8a : A0i8b;
    signed char* A1c = (t & 1) ? A1i8b : A1i8a;
    signed char* A1n = (t & 1) ? A1i8a : A1i8b;

    if (t == 0) {
      // bf16 path (z is unbounded N(0,1) -> int8 scale-127 would clip it)
      gemm_bf_cell_k<true><<<256, 512, 0, stream>>>(
          A0bf, Wc0, K0P, bc0, W0T, idx, c0,
          A0n, K0P, nullptr, 0,      // h0' int8 -> A0 for t=1
          A1bf, K1P);                // h0' bf16 -> A1bf for t=0 GEMM1
      gemm_bf_cell_k<false><<<256, 512, 0, stream>>>(
          A1bf, Wc1, K1P, bc1, nullptr, nullptr, c1,
          A1n + HIDDEN, K1P, nullptr, 0,   // h1' int8 -> A1 for t=1
          HL, HIDDEN);                     // h1' bf16 -> logits
    } else {
      gemm_i8_cell_k<true><<<256, 512, 0, stream>>>(
          A0c, Bpi0, K0P, bc0, SC0, W0T, idx, c0,
          A1c, K1P,                  // h0' -> A1 (current) first half
          A0n, K0P,                  // h0' -> A0 (next step)
          nullptr, 0);
      gemm_i8_cell_k<false><<<256, 512, 0, stream>>>(
          A1c, Bpi1, K1P, bc1, SC1, nullptr, nullptr, c1,
          A1n + HIDDEN, K1P, nullptr, 0,   // h1' -> A1 (next)
          HL, HIDDEN);                     // h1' bf16 -> logits
    }
    gemm_bt64_k<<<dim3(LGN / 128, BP / 64), dim3(256), 0, stream>>>(
        HL, HIDDEN, Wfp, HIDDEN, LG, LGN, HIDDEN);
    smax_k<<<BP, 64, 0, stream>>>(LG, bfv, out, t, x, A0n, idx);
  }
}

// Round 13
// 1704.769 us; speedup vs baseline: 1.4399x; 1.0805x over previous
//
#include <hip/hip_runtime.h>
#include <hip/hip_bf16.h>

#define HIDDEN   1024
#define XDIM     130
#define CONDDIM  44
#define INDIM    174      // XDIM + CONDDIM
#define NSTEP    16
#define BP       4096     // effective batch (64*64)
#define K0P      1088     // 1024 (h0) + 44 (y) + 20 pad ; i8: 17 tiles of 64
#define K1P      2048     // 1024 (h0') + 1024 (h1)      ; i8: 32 tiles of 64
#define GN       4096     // 4*HIDDEN gate dim
#define LGN      256      // padded logits cols (130 -> 256)

typedef float f32x4 __attribute__((ext_vector_type(4)));
typedef int   i32x4 __attribute__((ext_vector_type(4)));

// fused gate column order: n in [0,4096) -> q=(n>>4)&3 (gate), j=((n>>6)<<4)|(n&15)
__device__ __forceinline__ int fused_row(int n) {
  const int q = (n >> 4) & 3;
  const int j = ((n >> 6) << 4) | (n & 15);
  return q * HIDDEN + j;
}

__device__ __forceinline__ void g2lds16(const void* g, void* l) {
  __builtin_amdgcn_global_load_lds(
      (const __attribute__((address_space(1))) void*)g,
      (__attribute__((address_space(3))) void*)l, 16, 0, 0);
}

__device__ __forceinline__ float sigm(float x)  { return 1.f / (1.f + __expf(-x)); }
__device__ __forceinline__ float tanhfast(float x) { return 2.f / (1.f + __expf(-2.f * x)) - 1.f; }

__device__ __forceinline__ signed char qscale(float v, float inv127s) {
  // round(v * 127 / s) clipped; inv127s = 127/s
  int q = __float2int_rn(v * inv127s);
  q = q > 127 ? 127 : (q < -127 ? -127 : q);
  return (signed char)q;
}

// ================================================================ int8 gate GEMM + fused LSTM cell
// gates(4096 x 4096) = A(4096 x K) @ W(4096 x K)^T, fused-gate column order.
// R4 geometry: 8 waves (2M x 4N), 64B LDS rows (K=64 i8), 4 buffers, 3-ahead
// prefetch, counted vmcnt, XOR chunk swizzle (source pre-XORed, LDS linear).
// A int8: rows scaled by sA[b] (null -> 1, i.e. value = q/127).
// W int8: per-fused-row scale Rmax; SC[n] = Rmax[n]/127^2.
// Epilogue: gate = acc * SC[n] * sA[b] + bias (+ one-hot feedback via W0T);
// h quantized to d1 (scale sD1[b] or 1) and d2 (scale 1).
template<bool FB>
__global__ __launch_bounds__(512, 2)
void gemm_i8_cell_k(const signed char* __restrict__ A,
                    const signed char* __restrict__ W, int K,
                    const float* __restrict__ bcomb,
                    const float* __restrict__ SC,
                    const float* __restrict__ sA,        // per-row A scale (or null)
                    const float* __restrict__ W0T,
                    const int*   __restrict__ idx,
                    float* __restrict__ c,
                    signed char* __restrict__ d1, int ld1,
                    const float* __restrict__ sD1,       // d1 quant scale (or null)
                    signed char* __restrict__ d2, int ld2)
{
  __shared__ __align__(16) signed char lds[4 * 32768];   // 4 buf x (A 16KB + B 16KB)

  const int tid  = threadIdx.x;
  const int w    = tid >> 6;
  const int lane = tid & 63;
  const int bid  = blockIdx.x;
  const int swz  = ((bid & 7) << 5) | (bid >> 3);   // XCD-chunked (256 % 8 == 0)
  const int m0   = (swz >> 4) * 256;
  const int n0   = (swz & 15) * 256;
  const int wm   = w >> 2;
  const int wn   = w & 3;
  const int fr   = lane & 15;
  const int kqs  = (((lane >> 4) ^ ((fr >> 1) & 3)) * 16);   // byte chunk, swizzled
  const int sr   = lane >> 2;
  const int sc   = (((lane & 3) ^ ((sr >> 1) & 3)) * 16);    // source chunk, pre-XORed
  const int NT   = K >> 6;          // K-tiles of 64 int8 (64 B rows)

  i32x4 acc[8][4] = {};

  #define STAGE_A(t, d, i)                                                          \
    g2lds16(A + (size_t)(m0 + w * 32 + (i) * 16 + sr) * K + ((t) * 64 + sc),        \
            (void*)(lds + (d) * 32768 + (w * 32 + (i) * 16) * 64))
  #define STAGE_B(t, d, i)                                                          \
    g2lds16(W + (size_t)(n0 + w * 32 + (i) * 16 + sr) * K + ((t) * 64 + sc),        \
            (void*)(lds + (d) * 32768 + 16384 + (w * 32 + (i) * 16) * 64))

  const int npro = (NT < 3) ? NT : 3;
  for (int t = 0; t < npro; ++t) {
    STAGE_A(t, t, 0); STAGE_B(t, t, 0);
    STAGE_A(t, t, 1); STAGE_B(t, t, 1);
  }
  if (NT >= 3)      asm volatile("s_waitcnt vmcnt(8)" ::: "memory");
  else if (NT == 2) asm volatile("s_waitcnt vmcnt(4)" ::: "memory");
  else              asm volatile("s_waitcnt vmcnt(0)" ::: "memory");
  __builtin_amdgcn_s_barrier();

  for (int t = 0; t < NT; ++t) {
    const int d  = t & 3;
    const signed char* As = lds + d * 32768;
    const signed char* Bs = As + 16384;
    const int tp = t + 3;
    const int dp = tp & 3;
    const bool pf = tp < NT;

    i32x4 bfr[4];
    #pragma unroll
    for (int nf = 0; nf < 4; ++nf)
      bfr[nf] = *reinterpret_cast<const i32x4*>(&Bs[(wn * 64 + nf * 16 + fr) * 64 + kqs]);

    #pragma unroll
    for (int half = 0; half < 2; ++half) {
      if (pf) {
        if (half == 0) { STAGE_A(tp, dp, 0); STAGE_A(tp, dp, 1); }
        else           { STAGE_B(tp, dp, 0); STAGE_B(tp, dp, 1); }
      }
      i32x4 afr[4];
      #pragma unroll
      for (int q = 0; q < 4; ++q)
        afr[q] = *reinterpret_cast<const i32x4*>(&As[(wm * 128 + (half * 4 + q) * 16 + fr) * 64 + kqs]);
      __builtin_amdgcn_s_setprio(1);
      #pragma unroll
      for (int q = 0; q < 4; ++q)
        #pragma unroll
        for (int nf = 0; nf < 4; ++nf)
          acc[half * 4 + q][nf] =
              __builtin_amdgcn_mfma_i32_16x16x64_i8(afr[q], bfr[nf], acc[half * 4 + q][nf], 0, 0, 0);
      __builtin_amdgcn_s_setprio(0);
    }

    if (t + 3 < NT)      asm volatile("s_waitcnt vmcnt(8)" ::: "memory");
    else if (t + 2 < NT) asm volatile("s_waitcnt vmcnt(4)" ::: "memory");
    else if (t + 1 < NT) asm volatile("s_waitcnt vmcnt(0)" ::: "memory");
    if (t + 1 < NT) __builtin_amdgcn_s_barrier();
  }
  #undef STAGE_A
  #undef STAGE_B

  const int fq = lane >> 4;
  const int cb = n0 + wn * 64;
  const int j  = ((cb >> 6) << 4) | fr;

  const float bs0 = bcomb[cb + fr],      sc0 = SC[cb + fr];
  const float bs1 = bcomb[cb + 16 + fr], sc1 = SC[cb + 16 + fr];
  const float bs2 = bcomb[cb + 32 + fr], sc2 = SC[cb + 32 + fr];
  const float bs3 = bcomb[cb + 48 + fr], sc3 = SC[cb + 48 + fr];

  #pragma unroll
  for (int mf = 0; mf < 8; ++mf) {
    #pragma unroll
    for (int r = 0; r < 4; ++r) {
      const int b = m0 + wm * 128 + mf * 16 + fq * 4 + r;
      const float sa = sA ? sA[b] : 1.f;
      float gi = (float)acc[mf][0][r] * (sc0 * sa) + bs0;
      float gf = (float)acc[mf][1][r] * (sc1 * sa) + bs1;
      float gg = (float)acc[mf][2][r] * (sc2 * sa) + bs2;
      float go = (float)acc[mf][3][r] * (sc3 * sa) + bs3;
      if (FB) {
        const float* wr = W0T + (size_t)idx[b] * GN;
        gi += wr[cb + fr];
        gf += wr[cb + 16 + fr];
        gg += wr[cb + 32 + fr];
        go += wr[cb + 48 + fr];
      }
      const size_t ci = (size_t)b * HIDDEN + j;
      const float cn = sigm(gf) * c[ci] + sigm(gi) * tanhfast(gg);
      c[ci] = cn;
      const float hn = sigm(go) * tanhfast(cn);
      if (d1) {
        const float i127s = sD1 ? (127.f / sD1[b]) : 127.f;
        d1[(size_t)b * ld1 + j] = qscale(hn, i127s);
      }
      if (d2) d2[(size_t)b * ld2 + j] = qscale(hn, 127.f);
    }
  }
}

// ---------------------------------------------------------------- int8 logits GEMM (64x128 tile, 128 blocks)
// LG(4096 x 256) = h1'(int8, scale 1/127) @ Wfi^T ; LG fp32 = acc * SCf[col].
__global__ __launch_bounds__(256, 4)
void logits_i8_k(const signed char* __restrict__ A, int lda,   // h1' rows (stride K1P)
                 const signed char* __restrict__ Wfi,          // [256][1024] int8
                 const float* __restrict__ SCf,                // RMf/127^2
                 float* __restrict__ C, int ldc)
{
  __shared__ __align__(16) signed char As[64 * 64];    // 4 KB
  __shared__ __align__(16) signed char Bs[128 * 64];   // 8 KB

  const int tid  = threadIdx.x;
  const int w    = tid >> 6;
  const int lane = tid & 63;
  const int m0 = blockIdx.y * 64;
  const int n0 = blockIdx.x * 128;
  const int wm = w >> 1;
  const int wn = w & 1;
  const int fr = lane & 15;
  const int kqs = (((lane >> 4) ^ ((fr >> 1) & 3)) * 16);
  const int sr  = lane >> 2;
  const int sc  = (((lane & 3) ^ ((sr >> 1) & 3)) * 16);

  i32x4 acc[2][4] = {};

  for (int k0 = 0; k0 < HIDDEN; k0 += 64) {
    __syncthreads();
    g2lds16(A + (size_t)(m0 + w * 16 + sr) * lda + (k0 + sc), (void*)(As + (w * 16) * 64));
    g2lds16(Wfi + (size_t)(n0 + w * 16 + sr) * HIDDEN + (k0 + sc), (void*)(Bs + (w * 16) * 64));
    g2lds16(Wfi + (size_t)(n0 + 64 + w * 16 + sr) * HIDDEN + (k0 + sc), (void*)(Bs + (64 + w * 16) * 64));
    __syncthreads();

    i32x4 af[2], bw[4];
    #pragma unroll
    for (int i = 0; i < 2; ++i)
      af[i] = *reinterpret_cast<const i32x4*>(&As[(wm * 32 + i * 16 + fr) * 64 + kqs]);
    #pragma unroll
    for (int j = 0; j < 4; ++j)
      bw[j] = *reinterpret_cast<const i32x4*>(&Bs[(wn * 64 + j * 16 + fr) * 64 + kqs]);
    #pragma unroll
    for (int i = 0; i < 2; ++i)
      #pragma unroll
      for (int j = 0; j < 4; ++j)
        acc[i][j] = __builtin_amdgcn_mfma_i32_16x16x64_i8(af[i], bw[j], acc[i][j], 0, 0, 0);
  }

  const int fq = lane >> 4;
  #pragma unroll
  for (int i = 0; i < 2; ++i)
    #pragma unroll
    for (int j = 0; j < 4; ++j) {
      const int col = n0 + wn * 64 + j * 16 + fr;
      const float scf = SCf[col];
      #pragma unroll
      for (int r = 0; r < 4; ++r) {
        const int row = m0 + wm * 32 + i * 16 + fq * 4 + r;
        C[(size_t)row * ldc + col] = (float)acc[i][j][r] * scf;
      }
    }
}

// ---------------------------------------------------------------- log_softmax + argmax + y staging (int8)
__global__ void smax_k(const float* __restrict__ LG,
                       const float* __restrict__ bfv,
                       float* __restrict__ out, int t,
                       const float* __restrict__ x,
                       signed char* __restrict__ A0next,   // y cols: q127(y/4)
                       int* __restrict__ idx)
{
  const int b    = blockIdx.x;
  const int lane = threadIdx.x;   // 64
  const float NINF = -__builtin_inff();
  const float* lg = LG + (size_t)b * LGN;

  const int c1 = lane + 64, c2 = lane + 128;
  float v0 = lg[lane] + bfv[lane];
  float v1 = lg[c1] + bfv[c1];
  float v2 = (c2 < XDIM) ? lg[c2] + bfv[c2] : NINF;

  float m = fmaxf(v0, fmaxf(v1, v2));
  #pragma unroll
  for (int o = 32; o > 0; o >>= 1) m = fmaxf(m, __shfl_xor(m, o, 64));

  int bi = 0x7fffffff;
  if (v0 == m) bi = lane;
  if (v1 == m) bi = min(bi, c1);
  if (v2 == m) bi = min(bi, c2);
  #pragma unroll
  for (int o = 32; o > 0; o >>= 1) bi = min(bi, __shfl_xor(bi, o, 64));

  float s = __expf(v0 - m) + __expf(v1 - m) + ((c2 < XDIM) ? __expf(v2 - m) : 0.f);
  #pragma unroll
  for (int o = 32; o > 0; o >>= 1) s += __shfl_xor(s, o, 64);
  const float lse = __logf(s);

  float* orow = out + ((size_t)b * NSTEP + t) * XDIM;
  orow[lane] = v0 - m - lse;
  orow[c1]   = v1 - m - lse;
  if (c2 < XDIM) orow[c2] = v2 - m - lse;
  if (lane == 0) idx[b] = bi;

  if (t + 1 < NSTEP) {
    const float yv = (lane < CONDDIM)
        ? x[((size_t)b * NSTEP + (t + 1)) * INDIM + XDIM + lane] : 0.f;
    A0next[(size_t)b * K0P + HIDDEN + lane] = qscale(yv * 0.25f, 127.f);
  }
}

// ---------------------------------------------------------------- init: per-row scales + quantize z
// block = one batch row b (64 lanes). s0=max(|z|,|y0|/4), s1=max(1,|z|).
__global__ void initq_k(const float* __restrict__ z, const float* __restrict__ x,
                        float* __restrict__ c0, float* __restrict__ c1,
                        signed char* __restrict__ A0, signed char* __restrict__ A1,
                        float* __restrict__ S0, float* __restrict__ S1,
                        int* __restrict__ idx)
{
  const int b    = blockIdx.x;
  const int lane = threadIdx.x;   // 64
  const float* zr = z + (size_t)b * HIDDEN;

  float mz = 0.f;
  for (int k = lane; k < HIDDEN; k += 64) mz = fmaxf(mz, fabsf(zr[k]));
  #pragma unroll
  for (int o = 32; o > 0; o >>= 1) mz = fmaxf(mz, __shfl_xor(mz, o, 64));

  const float yv = (lane < CONDDIM) ? x[((size_t)b * NSTEP) * INDIM + XDIM + lane] : 0.f;
  float my = fabsf(yv) * 0.25f;
  #pragma unroll
  for (int o = 32; o > 0; o >>= 1) my = fmaxf(my, __shfl_xor(my, o, 64));

  const float s0 = fmaxf(fmaxf(mz, my), 1e-6f);
  const float s1 = fmaxf(mz, 1.f);
  const float i0 = 127.f / s0;
  const float i1 = 127.f / s1;

  for (int k = lane; k < HIDDEN; k += 64) {
    const float zv = zr[k];
    A0[(size_t)b * K0P + k]          = qscale(zv, i0);
    A1[(size_t)b * K1P + HIDDEN + k] = qscale(zv, i1);   // h1(-1) = z
    c0[(size_t)b * HIDDEN + k] = 0.f;
    c1[(size_t)b * HIDDEN + k] = 0.f;
  }
  // y_0 / 4 + zero pad (cols 1024..1087)
  A0[(size_t)b * K0P + HIDDEN + lane] = qscale(yv * 0.25f, i0);
  if (lane == 0) { S0[b] = s0; S1[b] = s1; idx[b] = 1; }
}

// ---------------------------------------------------------------- weight packing
__global__ void rowmax0_k(const float* __restrict__ Wih0, const float* __restrict__ Whh0,
                          float* __restrict__ RM, float* __restrict__ SC)
{
  const int n = blockIdx.x, lane = threadIdx.x;
  const int row = fused_row(n);
  float m = 1e-20f;
  for (int k = lane; k < HIDDEN; k += 64)  m = fmaxf(m, fabsf(Whh0[(size_t)row * HIDDEN + k]));
  for (int k = lane; k < CONDDIM; k += 64) m = fmaxf(m, 4.f * fabsf(Wih0[(size_t)row * INDIM + XDIM + k]));
  #pragma unroll
  for (int o = 32; o > 0; o >>= 1) m = fmaxf(m, __shfl_xor(m, o, 64));
  if (lane == 0) { RM[n] = m; SC[n] = m / 16129.f; }
}

__global__ void rowmax1_k(const float* __restrict__ Wih1, const float* __restrict__ Whh1,
                          float* __restrict__ RM, float* __restrict__ SC)
{
  const int n = blockIdx.x, lane = threadIdx.x;
  const int row = fused_row(n);
  float m = 1e-20f;
  for (int k = lane; k < HIDDEN; k += 64) {
    m = fmaxf(m, fabsf(Wih1[(size_t)row * HIDDEN + k]));
    m = fmaxf(m, fabsf(Whh1[(size_t)row * HIDDEN + k]));
  }
  #pragma unroll
  for (int o = 32; o > 0; o >>= 1) m = fmaxf(m, __shfl_xor(m, o, 64));
  if (lane == 0) { RM[n] = m; SC[n] = m / 16129.f; }
}

__global__ void packi0_k(const float* __restrict__ Wih0, const float* __restrict__ Whh0,
                         const float* __restrict__ RM, signed char* __restrict__ Bp)
{
  const int t = blockIdx.x * blockDim.x + threadIdx.x;
  if (t >= GN * K0P) return;
  const int n = t / K0P, k = t % K0P;
  const int row = fused_row(n);
  float v = 0.f;
  if (k < HIDDEN)                v = Whh0[(size_t)row * HIDDEN + k];
  else if (k < HIDDEN + CONDDIM) v = 4.f * Wih0[(size_t)row * INDIM + XDIM + (k - HIDDEN)];
  Bp[t] = qscale(v, 127.f / RM[n]);
}

__global__ void packi1_k(const float* __restrict__ Wih1, const float* __restrict__ Whh1,
                         const float* __restrict__ RM, signed char* __restrict__ Bp)
{
  const int t = blockIdx.x * blockDim.x + threadIdx.x;
  if (t >= GN * K1P) return;
  const int n = t >> 11, k = t & 2047;
  const int row = fused_row(n);
  const float v = (k < HIDDEN) ? Wih1[(size_t)row * HIDDEN + k]
                               : Whh1[(size_t)row * HIDDEN + (k - HIDDEN)];
  Bp[t] = qscale(v, 127.f / RM[n]);
}

__global__ void packbias_k(const float* __restrict__ bih, const float* __restrict__ bhh,
                           float* __restrict__ bc)
{
  const int n = blockIdx.x * blockDim.x + threadIdx.x;
  if (n >= GN) return;
  const int row = fused_row(n);
  bc[n] = bih[row] + bhh[row];
}

__global__ void rowmaxf_k(const float* __restrict__ Wf, float* __restrict__ RM,
                          float* __restrict__ SC)
{
  const int n = blockIdx.x, lane = threadIdx.x;
  float m = 1e-20f;
  if (n < XDIM)
    for (int k = lane; k < HIDDEN; k += 64) m = fmaxf(m, fabsf(Wf[(size_t)n * HIDDEN + k]));
  else m = 1.f;
  #pragma unroll
  for (int o = 32; o > 0; o >>= 1) m = fmaxf(m, __shfl_xor(m, o, 64));
  if (lane == 0) { RM[n] = m; SC[n] = m / 16129.f; }
}

__global__ void packfi_k(const float* __restrict__ Wf, const float* __restrict__ RM,
                         signed char* __restrict__ Wfi)
{
  const int t = blockIdx.x * blockDim.x + threadIdx.x;
  if (t >= LGN * HIDDEN) return;
  const int r = t >> 10, k = t & 1023;
  const float v = (r < XDIM) ? Wf[(size_t)r * HIDDEN + k] : 0.f;
  Wfi[t] = qscale(v, 127.f / RM[r]);
}

__global__ void packt_k(const float* __restrict__ Wih0, float* __restrict__ W0T)
{
  const int t = blockIdx.x * blockDim.x + threadIdx.x;
  if (t >= XDIM * GN) return;
  const int e = t >> 12, n = t & 4095;
  W0T[t] = Wih0[(size_t)fused_row(n) * INDIM + e];
}

// ---------------------------------------------------------------- launch
extern "C" void kernel_launch(void* const* d_in, const int* in_sizes, int n_in,
                              void* d_out, int out_size, void* d_ws, size_t ws_size,
                              hipStream_t stream)
{
  const float* z    = (const float*)d_in[0];
  const float* x    = (const float*)d_in[1];
  const float* Wih0 = (const float*)d_in[2];
  const float* Whh0 = (const float*)d_in[3];
  const float* bih0 = (const float*)d_in[4];
  const float* bhh0 = (const float*)d_in[5];
  const float* Wih1 = (const float*)d_in[6];
  const float* Whh1 = (const float*)d_in[7];
  const float* bih1 = (const float*)d_in[8];
  const float* bhh1 = (const float*)d_in[9];
  const float* Wf   = (const float*)d_in[10];
  const float* bfv  = (const float*)d_in[11];
  float* out = (float*)d_out;

  char* ws = (char*)d_ws;
  size_t off = 0;
  auto alloc = [&](size_t bytes) { void* p = ws + off; off += (bytes + 255) & ~(size_t)255; return p; };

  float*       LG    = (float*)      alloc((size_t)BP * LGN * 4);
  signed char* A0i8a = (signed char*)alloc((size_t)BP * K0P);
  signed char* A0i8b = (signed char*)alloc((size_t)BP * K0P);
  signed char* A1i8a = (signed char*)alloc((size_t)BP * K1P);
  signed char* A1i8b = (signed char*)alloc((size_t)BP * K1P);
  signed char* Bpi0  = (signed char*)alloc((size_t)GN * K0P);
  signed char* Bpi1  = (signed char*)alloc((size_t)GN * K1P);
  signed char* Wfi   = (signed char*)alloc((size_t)LGN * HIDDEN);
  float*       W0T   = (float*)      alloc((size_t)XDIM * GN * 4);
  float*       bc0   = (float*)      alloc((size_t)GN * 4);
  float*       bc1   = (float*)      alloc((size_t)GN * 4);
  float*       RM0   = (float*)      alloc((size_t)GN * 4);
  float*       SC0   = (float*)      alloc((size_t)GN * 4);
  float*       RM1   = (float*)      alloc((size_t)GN * 4);
  float*       SC1   = (float*)      alloc((size_t)GN * 4);
  float*       RMf   = (float*)      alloc((size_t)LGN * 4);
  float*       SCf   = (float*)      alloc((size_t)LGN * 4);
  float*       S0    = (float*)      alloc((size_t)BP * 4);
  float*       S1    = (float*)      alloc((size_t)BP * 4);
  float*       c0    = (float*)      alloc((size_t)BP * HIDDEN * 4);
  float*       c1    = (float*)      alloc((size_t)BP * HIDDEN * 4);
  int*         idx   = (int*)        alloc((size_t)BP * 4);
  (void)ws_size; (void)in_sizes; (void)n_in; (void)out_size;

  rowmax0_k<<<GN, 64, 0, stream>>>(Wih0, Whh0, RM0, SC0);
  rowmax1_k<<<GN, 64, 0, stream>>>(Wih1, Whh1, RM1, SC1);
  rowmaxf_k<<<LGN, 64, 0, stream>>>(Wf, RMf, SCf);
  packi0_k<<<(GN * K0P + 255) / 256, 256, 0, stream>>>(Wih0, Whh0, RM0, Bpi0);
  packi1_k<<<(GN * K1P + 255) / 256, 256, 0, stream>>>(Wih1, Whh1, RM1, Bpi1);
  packfi_k<<<(LGN * HIDDEN + 255) / 256, 256, 0, stream>>>(Wf, RMf, Wfi);
  packbias_k<<<(GN + 255) / 256, 256, 0, stream>>>(bih0, bhh0, bc0);
  packbias_k<<<(GN + 255) / 256, 256, 0, stream>>>(bih1, bhh1, bc1);
  packt_k<<<(XDIM * GN + 255) / 256, 256, 0, stream>>>(Wih0, W0T);
  initq_k<<<BP, 64, 0, stream>>>(z, x, c0, c1, A0i8a, A1i8a, S0, S1, idx);

  for (int t = 0; t < NSTEP; ++t) {
    signed char* A0c = (t & 1) ? A0i8b : A0i8a;
    signed char* A0n = (t & 1) ? A0i8a : A0i8b;
    signed char* A1c = (t & 1) ? A1i8b : A1i8a;
    signed char* A1n = (t & 1) ? A1i8a : A1i8b;
    const float* sA0 = (t == 0) ? S0 : nullptr;   // A0 row scales (t=0: [z|y])
    const float* sA1 = (t == 0) ? S1 : nullptr;   // A1 row scales (t=0: [h0'|z])
    const float* sD1 = (t == 0) ? S1 : nullptr;   // h0' -> A1c quant scale at t=0

    // layer 0: fused cell -> h0'
    gemm_i8_cell_k<true><<<256, 512, 0, stream>>>(
        A0c, Bpi0, K0P, bc0, SC0, sA0, W0T, idx, c0,
        A1c, K1P, sD1,           // h0' -> A1 (current) first half
        A0n, K0P);               // h0' -> A0 (next step), scale 1
    // layer 1: fused cell -> h1'
    gemm_i8_cell_k<false><<<256, 512, 0, stream>>>(
        A1c, Bpi1, K1P, bc1, SC1, sA1, nullptr, nullptr, c1,
        A1n + HIDDEN, K1P, nullptr,   // h1' -> A1 (next) second half, scale 1
        nullptr, 0);
    // logits from int8 h1' (scale 1/127)
    logits_i8_k<<<dim3(LGN / 128, BP / 64), dim3(256), 0, stream>>>(
        A1n + HIDDEN, K1P, Wfi, SCf, LG, LGN);
    smax_k<<<BP, 64, 0, stream>>>(LG, bfv, out, t, x, A0n, idx);
  }
}